// Round 3
// baseline (2003.911 us; speedup 1.0000x reference)
//
#include <hip/hip_runtime.h>
#include <math.h>

#define NL 10
#define BSZ 2
#define TSEQ 2040
#define TPAD 2048
#define DMOD 256
#define NH 4
#define HDIM 64
#define DFF 1024
#define MPAD (BSZ*TPAD)   // 4096
#define CKV 256           // KV chunk per attention wave-unit
#define NCH 8             // 2048/CKV chunks max

typedef __attribute__((ext_vector_type(8))) short bf16x8;
typedef __attribute__((ext_vector_type(4))) float f32x4;

__device__ __forceinline__ ushort f2b(float f){
  union { float f; unsigned u; } v; v.f = f;
  unsigned u = v.u;
  return (ushort)((u + 0x7FFFu + ((u >> 16) & 1u)) >> 16);
}
__device__ __forceinline__ float b2f(ushort h){
  union { unsigned u; float f; } v; v.u = ((unsigned)h) << 16; return v.f;
}

// ---- copy sequences (B,2040,256) -> padded x [B][2048][256] f32 ----
__global__ __launch_bounds__(256) void copy_in_k(const float* __restrict__ seq, float* __restrict__ x){
  int idx = blockIdx.x * 256 + threadIdx.x;
  int row = idx >> 6, c = idx & 63;
  if (row >= BSZ * TSEQ) return;
  int b = row / TSEQ, t = row % TSEQ;
  ((float4*)(x + (size_t)(b * TPAD + t) * DMOD))[c] = ((const float4*)(seq + (size_t)row * DMOD))[c];
}

// ---- transpose+cast weights: src (L,K,N) f32 -> dst rows [l][row0+n][k] bf16 ----
__global__ __launch_bounds__(256) void wtrans_k(const float* __restrict__ src, ushort* __restrict__ dst,
                                                int N, int K, int NTOT, int row0, int total){
  int idx = blockIdx.x * 256 + threadIdx.x;
  if (idx >= total) return;
  int kk = idx % K; int rem = idx / K; int n = rem % N; int l = rem / N;
  dst[((size_t)(l * NTOT + row0 + n)) * K + kk] = f2b(src[((size_t)(l * K + kk)) * N + n]);
}

// ---- concat qkv biases ----
__global__ __launch_bounds__(256) void bqkv_k(const float* __restrict__ bq, const float* __restrict__ bk,
                                              const float* __restrict__ bv, float* __restrict__ bqkv){
  int idx = blockIdx.x * 256 + threadIdx.x;
  if (idx >= NL * 768) return;
  int l = idx / 768, n = idx % 768;
  float v = (n < 256) ? bq[l * 256 + n] : ((n < 512) ? bk[l * 256 + n - 256] : bv[l * 256 + n - 512]);
  bqkv[idx] = v;
}

// ---- final layernorm -> f32 d_out (compact rows) ----
__global__ __launch_bounds__(64) void lnf_k(const float* __restrict__ x, const float* __restrict__ g,
                                            const float* __restrict__ be, float* __restrict__ outf){
  int row = blockIdx.x, lane = threadIdx.x;
  int b = row / TSEQ, t = row % TSEQ;
  int irow = b * TPAD + t;
  float4 xv = ((const float4*)(x + (size_t)irow * DMOD))[lane];
  float s  = xv.x + xv.y + xv.z + xv.w;
  float s2 = xv.x*xv.x + xv.y*xv.y + xv.z*xv.z + xv.w*xv.w;
  #pragma unroll
  for (int off = 1; off < 64; off <<= 1){ s += __shfl_xor(s, off); s2 += __shfl_xor(s2, off); }
  float mu = s * (1.f/256.f);
  float var = s2 * (1.f/256.f) - mu * mu;
  float rs = rsqrtf(var + 1e-5f);
  float4 gv = ((const float4*)g)[lane];
  float4 bv = ((const float4*)be)[lane];
  float4 ov;
  ov.x = (xv.x - mu) * rs * gv.x + bv.x;
  ov.y = (xv.y - mu) * rs * gv.y + bv.y;
  ov.z = (xv.z - mu) * rs * gv.z + bv.z;
  ov.w = (xv.w - mu) * rs * gv.w + bv.w;
  ((float4*)(outf + (size_t)row * DMOD))[lane] = ov;
}

// ---- K=256 GEMM, full-K LDS staging, single barrier, optional fused LN on A ----
// LNA=1: A from f32 x with per-row LayerNorm (g,be). LNA=0: A bf16 direct.
// EPI 0: QKV scatter; EPI 1: residual add into xres; EPI 2: tanh-GELU -> o0 bf16 [M][N]
template<int N, int EPI, int LNA>
__global__ __launch_bounds__(256) void gemm256_k(const float* __restrict__ Af, const ushort* __restrict__ Ab,
                                                 const ushort* __restrict__ Bt,
                                                 const float* __restrict__ g, const float* __restrict__ be,
                                                 const float* __restrict__ bias, float* __restrict__ xres,
                                                 ushort* __restrict__ o0, ushort* __restrict__ o1,
                                                 ushort* __restrict__ o2){
  __shared__ ushort Alds[64][264];
  __shared__ ushort Blds[64][264];
  int tid = threadIdx.x;
  int row0 = blockIdx.x * 64, col0 = blockIdx.y * 64;
  int r = tid >> 2, q = tid & 3;          // 4 threads per row, each owns 64 cols
  // stage B tile (bf16 weights, rows = output cols)
  {
    const ushort* src = Bt + (size_t)(col0 + r) * 256 + q * 64;
    #pragma unroll
    for (int i = 0; i < 8; ++i)
      *(bf16x8*)&Blds[r][q * 64 + i * 8] = *(const bf16x8*)(src + i * 8);
  }
  // stage A tile
  if (LNA){
    const float4* src = (const float4*)(Af + (size_t)(row0 + r) * 256 + q * 64);
    float4 xv[16];
    float s = 0.f, s2 = 0.f;
    #pragma unroll
    for (int i = 0; i < 16; ++i){
      xv[i] = src[i];
      s  += xv[i].x + xv[i].y + xv[i].z + xv[i].w;
      s2 += xv[i].x*xv[i].x + xv[i].y*xv[i].y + xv[i].z*xv[i].z + xv[i].w*xv[i].w;
    }
    s += __shfl_xor(s, 1); s2 += __shfl_xor(s2, 1);
    s += __shfl_xor(s, 2); s2 += __shfl_xor(s2, 2);
    float mu = s * (1.f/256.f);
    float var = s2 * (1.f/256.f) - mu * mu;
    float rs = rsqrtf(var + 1e-5f);
    const float4* g4 = (const float4*)(g + q * 64);
    const float4* b4 = (const float4*)(be + q * 64);
    #pragma unroll
    for (int i = 0; i < 16; i += 2){
      float4 ga = g4[i], gb = g4[i+1], ba = b4[i], bb = b4[i+1];
      bf16x8 pk;
      pk[0] = (short)f2b((xv[i].x   - mu) * rs * ga.x + ba.x);
      pk[1] = (short)f2b((xv[i].y   - mu) * rs * ga.y + ba.y);
      pk[2] = (short)f2b((xv[i].z   - mu) * rs * ga.z + ba.z);
      pk[3] = (short)f2b((xv[i].w   - mu) * rs * ga.w + ba.w);
      pk[4] = (short)f2b((xv[i+1].x - mu) * rs * gb.x + bb.x);
      pk[5] = (short)f2b((xv[i+1].y - mu) * rs * gb.y + bb.y);
      pk[6] = (short)f2b((xv[i+1].z - mu) * rs * gb.z + bb.z);
      pk[7] = (short)f2b((xv[i+1].w - mu) * rs * gb.w + bb.w);
      *(bf16x8*)&Alds[r][q * 64 + i * 4] = pk;
    }
  } else {
    const ushort* src = Ab + (size_t)(row0 + r) * 256 + q * 64;
    #pragma unroll
    for (int i = 0; i < 8; ++i)
      *(bf16x8*)&Alds[r][q * 64 + i * 8] = *(const bf16x8*)(src + i * 8);
  }
  __syncthreads();

  int w = tid >> 6, lane = tid & 63;
  int wr = w >> 1, wc = w & 1;
  int l15 = lane & 15, l4 = lane >> 4;
  f32x4 zero = {0.f, 0.f, 0.f, 0.f};
  f32x4 acc[2][2];
  acc[0][0] = zero; acc[0][1] = zero; acc[1][0] = zero; acc[1][1] = zero;
  #pragma unroll
  for (int ks = 0; ks < 8; ++ks){
    bf16x8 af[2], bfr[2];
    #pragma unroll
    for (int i = 0; i < 2; ++i){
      af[i]  = *(const bf16x8*)&Alds[wr * 32 + i * 16 + l15][ks * 32 + l4 * 8];
      bfr[i] = *(const bf16x8*)&Blds[wc * 32 + i * 16 + l15][ks * 32 + l4 * 8];
    }
    #pragma unroll
    for (int mr = 0; mr < 2; ++mr)
      #pragma unroll
      for (int nc = 0; nc < 2; ++nc)
        acc[mr][nc] = __builtin_amdgcn_mfma_f32_16x16x32_bf16(af[mr], bfr[nc], acc[mr][nc], 0, 0, 0);
  }
  #pragma unroll
  for (int mr = 0; mr < 2; ++mr){
    #pragma unroll
    for (int nc = 0; nc < 2; ++nc){
      #pragma unroll
      for (int rr = 0; rr < 4; ++rr){
        int m = row0 + wr * 32 + mr * 16 + l4 * 4 + rr;
        int n = col0 + wc * 32 + nc * 16 + l15;
        float v = acc[mr][nc][rr] + bias[n];
        if (EPI == 0){
          int b = m >> 11, t = m & 2047;
          int which = n >> 8, hn = n & 255, hh = hn >> 6, hd = hn & 63;
          if (which == 0)      o0[(((size_t)(b * NH + hh)) * TPAD + t) * HDIM + hd] = f2b(v);
          else if (which == 1) o1[(((size_t)(b * NH + hh)) * TPAD + t) * HDIM + hd] = f2b(v);
          else                 o2[(((size_t)(b * NH + hh)) * HDIM + hd) * TPAD + t] = f2b(v);
        } else if (EPI == 1){
          xres[(size_t)m * 256 + n] += v;
        } else {
          // tanh-form GELU (|err| ~1e-3 vs exact erf — well inside tolerance)
          float u = 0.7978845608028654f * (v + 0.044715f * v * v * v);
          float e = __expf(2.f * u);
          float th = 1.f - 2.f / (e + 1.f);
          o0[(size_t)m * N + n] = f2b(0.5f * v * (1.f + th));
        }
      }
    }
  }
}

// ---- generic looped GEMM (used for MLP2, K=1024), residual-add epilogue ----
template<int N, int K>
__global__ __launch_bounds__(256) void gemm_k(const ushort* __restrict__ A, const ushort* __restrict__ Bt,
                                              const float* __restrict__ bias, float* __restrict__ xres){
  __shared__ ushort Alds[64][72];
  __shared__ ushort Blds[64][72];
  int tid = threadIdx.x;
  int w = tid >> 6, lane = tid & 63;
  int wr = w >> 1, wc = w & 1;
  int l15 = lane & 15, l4 = lane >> 4;
  int row0 = blockIdx.x * 64, col0 = blockIdx.y * 64;
  f32x4 zero = {0.f, 0.f, 0.f, 0.f};
  f32x4 acc[2][2];
  acc[0][0] = zero; acc[0][1] = zero; acc[1][0] = zero; acc[1][1] = zero;
  int r = tid >> 3, c8 = (tid & 7) * 8;
  for (int k0 = 0; k0 < K; k0 += 64){
    #pragma unroll
    for (int it = 0; it < 2; ++it){
      int rr = r + it * 32;
      *(bf16x8*)&Alds[rr][c8] = *(const bf16x8*)(A  + (size_t)(row0 + rr) * K + k0 + c8);
      *(bf16x8*)&Blds[rr][c8] = *(const bf16x8*)(Bt + (size_t)(col0 + rr) * K + k0 + c8);
    }
    __syncthreads();
    #pragma unroll
    for (int ks = 0; ks < 2; ++ks){
      bf16x8 af[2], bfr[2];
      #pragma unroll
      for (int i = 0; i < 2; ++i){
        af[i]  = *(const bf16x8*)&Alds[wr * 32 + i * 16 + l15][ks * 32 + l4 * 8];
        bfr[i] = *(const bf16x8*)&Blds[wc * 32 + i * 16 + l15][ks * 32 + l4 * 8];
      }
      #pragma unroll
      for (int mr = 0; mr < 2; ++mr)
        #pragma unroll
        for (int nc = 0; nc < 2; ++nc)
          acc[mr][nc] = __builtin_amdgcn_mfma_f32_16x16x32_bf16(af[mr], bfr[nc], acc[mr][nc], 0, 0, 0);
    }
    __syncthreads();
  }
  #pragma unroll
  for (int mr = 0; mr < 2; ++mr){
    #pragma unroll
    for (int nc = 0; nc < 2; ++nc){
      #pragma unroll
      for (int rr = 0; rr < 4; ++rr){
        int m = row0 + wr * 32 + mr * 16 + l4 * 4 + rr;
        int n = col0 + wc * 32 + nc * 16 + l15;
        xres[(size_t)m * 256 + n] += acc[mr][nc][rr] + bias[n];
      }
    }
  }
}

// ---- split-KV flash attention, wave-independent 16-row x 256-KV units ----
// u = (bh<<10) | (qt<<3) | ch ; grid 2048 blocks x 4 waves = 8192 units.
__global__ __launch_bounds__(256) void attn_part_k(const ushort* __restrict__ qq, const ushort* __restrict__ kkk,
                                                   const ushort* __restrict__ vt,
                                                   ushort* __restrict__ po, float* __restrict__ pml){
  __shared__ ushort Plds[4][16][72];
  int tid = threadIdx.x, w = tid >> 6, lane = tid & 63;
  int l15 = lane & 15, l4 = lane >> 4;
  int u = blockIdx.x * 4 + w;
  int bh = u >> 10, qt = (u >> 3) & 127, ch = u & 7;
  int i0 = qt * 16;
  int je = ((i0 + 15) / 17) * 17 + 17; je = je < TSEQ ? je : TSEQ;   // max visible j (excl)
  int jstart = ch * CKV;
  if (jstart >= je) return;                       // idle unit
  int jend_w = (jstart + CKV) < je ? (jstart + CKV) : je;

  const ushort* qb = qq  + (size_t)bh * TPAD * HDIM;
  const ushort* kb = kkk + (size_t)bh * TPAD * HDIM;
  const ushort* vb = vt  + (size_t)bh * HDIM * TPAD;

  int qrow = i0 + l15;
  bf16x8 aq[2];
  aq[0] = *(const bf16x8*)(qb + (size_t)qrow * HDIM + l4 * 8);
  aq[1] = *(const bf16x8*)(qb + (size_t)qrow * HDIM + 32 + l4 * 8);

  float m_[4], l_[4];
  f32x4 zero = {0.f, 0.f, 0.f, 0.f};
  f32x4 o_[4];
  #pragma unroll
  for (int i = 0; i < 4; ++i){ m_[i] = -1e30f; l_[i] = 0.f; o_[i] = zero; }

  #pragma unroll 2
  for (int j0 = jstart; j0 < jend_w; j0 += 64){
    f32x4 s[4];
    s[0] = zero; s[1] = zero; s[2] = zero; s[3] = zero;
    #pragma unroll
    for (int ks = 0; ks < 2; ++ks){
      #pragma unroll
      for (int f = 0; f < 4; ++f){
        bf16x8 kf = *(const bf16x8*)(kb + (size_t)(j0 + f * 16 + l15) * HDIM + ks * 32 + l4 * 8);
        s[f] = __builtin_amdgcn_mfma_f32_16x16x32_bf16(aq[ks], kf, s[f], 0, 0, 0);
      }
    }
    #pragma unroll
    for (int rr = 0; rr < 4; ++rr){
      int ig = i0 + l4 * 4 + rr;
      float mx = -INFINITY;
      #pragma unroll
      for (int f = 0; f < 4; ++f){
        int jg = j0 + f * 16 + l15;
        float sv = s[f][rr] * 0.125f;
        bool ok = (jg <= ig) || ((ig / 17) == (jg / 17));
        sv = ok ? sv : -INFINITY;
        s[f][rr] = sv;
        mx = fmaxf(mx, sv);
      }
      #pragma unroll
      for (int off = 1; off < 16; off <<= 1) mx = fmaxf(mx, __shfl_xor(mx, off));
      float mn = fmaxf(fmaxf(m_[rr], mx), -1e30f);
      float alpha = __expf(m_[rr] - mn);
      float ps = 0.f;
      #pragma unroll
      for (int f = 0; f < 4; ++f){
        float p = __expf(s[f][rr] - mn);
        ps += p;
        Plds[w][l4 * 4 + rr][f * 16 + l15] = f2b(p);
      }
      #pragma unroll
      for (int off = 1; off < 16; off <<= 1) ps += __shfl_xor(ps, off);
      l_[rr] = l_[rr] * alpha + ps;
      m_[rr] = mn;
      #pragma unroll
      for (int f = 0; f < 4; ++f) o_[f][rr] *= alpha;
    }
    #pragma unroll
    for (int ks = 0; ks < 2; ++ks){
      bf16x8 pf = *(const bf16x8*)&Plds[w][l15][ks * 32 + l4 * 8];
      #pragma unroll
      for (int f = 0; f < 4; ++f){
        bf16x8 vf = *(const bf16x8*)(vb + (size_t)(f * 16 + l15) * TPAD + j0 + ks * 32 + l4 * 8);
        o_[f] = __builtin_amdgcn_mfma_f32_16x16x32_bf16(pf, vf, o_[f], 0, 0, 0);
      }
    }
  }
  // partials: po[u][16][64] bf16, pml[u][16][2] f32
  size_t ob = (size_t)u * 1024;
  #pragma unroll
  for (int rr = 0; rr < 4; ++rr){
    int r16 = l4 * 4 + rr;
    #pragma unroll
    for (int f = 0; f < 4; ++f)
      po[ob + r16 * 64 + f * 16 + l15] = f2b(o_[f][rr]);
    if (l15 == 0){
      pml[(size_t)u * 32 + r16 * 2 + 0] = m_[rr];
      pml[(size_t)u * 32 + r16 * 2 + 1] = l_[rr];
    }
  }
}

// ---- merge partials -> y bf16 [b][t pad][D] ----
__global__ __launch_bounds__(64) void attn_merge_k(const ushort* __restrict__ po, const float* __restrict__ pml,
                                                   ushort* __restrict__ y){
  int qt = blockIdx.x, bh = blockIdx.y;
  int b = bh >> 2, hh = bh & 3;
  int d = threadIdx.x;
  int i0 = qt * 16;
  int je = ((i0 + 15) / 17) * 17 + 17; je = je < TSEQ ? je : TSEQ;
  int nch = (je + CKV - 1) / CKV;
  int u0 = ((bh << 7) + qt) << 3;
  for (int r = 0; r < 16; ++r){
    float mg = -1e30f;
    for (int ch = 0; ch < nch; ++ch)
      mg = fmaxf(mg, pml[(size_t)(u0 + ch) * 32 + r * 2]);
    float lg = 0.f, o = 0.f;
    for (int ch = 0; ch < nch; ++ch){
      float mm = pml[(size_t)(u0 + ch) * 32 + r * 2];
      float ll = pml[(size_t)(u0 + ch) * 32 + r * 2 + 1];
      float a = __expf(mm - mg);
      lg += a * ll;
      o  += a * b2f(po[(size_t)(u0 + ch) * 1024 + r * 64 + d]);
    }
    y[((size_t)(b * TPAD + i0 + r)) * DMOD + hh * HDIM + d] = f2b(o / lg);
  }
}

extern "C" void kernel_launch(void* const* d_in, const int* in_sizes, int n_in,
                              void* d_out, int out_size, void* d_ws, size_t ws_size,
                              hipStream_t stream){
  const float* seq    = (const float*)d_in[0];
  const float* ln1_g  = (const float*)d_in[1];
  const float* ln1_b  = (const float*)d_in[2];
  const float* wq     = (const float*)d_in[3];
  const float* bq     = (const float*)d_in[4];
  const float* wk     = (const float*)d_in[5];
  const float* bk     = (const float*)d_in[6];
  const float* wv     = (const float*)d_in[7];
  const float* bv     = (const float*)d_in[8];
  const float* wproj  = (const float*)d_in[9];
  const float* bproj  = (const float*)d_in[10];
  const float* ln2_g  = (const float*)d_in[11];
  const float* ln2_b  = (const float*)d_in[12];
  const float* w1     = (const float*)d_in[13];
  const float* b1     = (const float*)d_in[14];
  const float* w2     = (const float*)d_in[15];
  const float* b2     = (const float*)d_in[16];
  const float* lnf_g  = (const float*)d_in[17];
  const float* lnf_b  = (const float*)d_in[18];

  size_t off = 0;
  char* base = (char*)d_ws;
  auto carve = [&](size_t bytes) -> void* {
    void* p = base + off;
    off += (bytes + 255) & ~(size_t)255;
    return p;
  };
  float*  x      = (float*) carve((size_t)MPAD * DMOD * 4);
  ushort* qbuf   = (ushort*)carve((size_t)BSZ * NH * TPAD * HDIM * 2);
  ushort* kbuf   = (ushort*)carve((size_t)BSZ * NH * TPAD * HDIM * 2);
  ushort* vtbuf  = (ushort*)carve((size_t)BSZ * NH * TPAD * HDIM * 2);
  ushort* ybuf   = (ushort*)carve((size_t)MPAD * DMOD * 2);
  ushort* mid    = (ushort*)carve((size_t)MPAD * DFF * 2);
  ushort* wqkvT  = (ushort*)carve((size_t)NL * 768 * 256 * 2);
  ushort* wprojT = (ushort*)carve((size_t)NL * 256 * 256 * 2);
  ushort* w1T    = (ushort*)carve((size_t)NL * 1024 * 256 * 2);
  ushort* w2T    = (ushort*)carve((size_t)NL * 256 * 1024 * 2);
  float*  bqkv   = (float*) carve((size_t)NL * 768 * 4);
  ushort* po     = (ushort*)carve((size_t)8192 * 1024 * 2);
  float*  pml    = (float*) carve((size_t)8192 * 32 * 4);
  if (off > ws_size) return;  // workspace too small; bail

  // input copy + weight prep
  copy_in_k<<<dim3((BSZ*TSEQ*64 + 255)/256), dim3(256), 0, stream>>>(seq, x);
  int tot;
  tot = NL*256*256;  wtrans_k<<<dim3((tot+255)/256), dim3(256), 0, stream>>>(wq,    wqkvT,  256, 256,  768, 0,   tot);
  tot = NL*256*256;  wtrans_k<<<dim3((tot+255)/256), dim3(256), 0, stream>>>(wk,    wqkvT,  256, 256,  768, 256, tot);
  tot = NL*256*256;  wtrans_k<<<dim3((tot+255)/256), dim3(256), 0, stream>>>(wv,    wqkvT,  256, 256,  768, 512, tot);
  tot = NL*256*256;  wtrans_k<<<dim3((tot+255)/256), dim3(256), 0, stream>>>(wproj, wprojT, 256, 256,  256, 0,   tot);
  tot = NL*1024*256; wtrans_k<<<dim3((tot+255)/256), dim3(256), 0, stream>>>(w1,    w1T,   1024, 256, 1024, 0,   tot);
  tot = NL*256*1024; wtrans_k<<<dim3((tot+255)/256), dim3(256), 0, stream>>>(w2,    w2T,    256,1024,  256, 0,   tot);
  bqkv_k<<<dim3((NL*768 + 255)/256), dim3(256), 0, stream>>>(bq, bk, bv, bqkv);

  for (int l = 0; l < NL; ++l){
    gemm256_k<768,0,1><<<dim3(64,12), dim3(256), 0, stream>>>(
        x, nullptr, wqkvT + (size_t)l*768*256, ln1_g + l*256, ln1_b + l*256,
        bqkv + l*768, nullptr, qbuf, kbuf, vtbuf);
    attn_part_k<<<dim3(2048), dim3(256), 0, stream>>>(qbuf, kbuf, vtbuf, po, pml);
    attn_merge_k<<<dim3(128, 8), dim3(64), 0, stream>>>(po, pml, ybuf);
    gemm256_k<256,1,0><<<dim3(64,4), dim3(256), 0, stream>>>(
        nullptr, ybuf, wprojT + (size_t)l*256*256, nullptr, nullptr,
        bproj + l*256, x, nullptr, nullptr, nullptr);
    gemm256_k<1024,2,1><<<dim3(64,16), dim3(256), 0, stream>>>(
        x, nullptr, w1T + (size_t)l*1024*256, ln2_g + l*256, ln2_b + l*256,
        b1 + l*1024, nullptr, mid, nullptr, nullptr);
    gemm_k<256,1024><<<dim3(64,4), dim3(256), 0, stream>>>(
        mid, w2T + (size_t)l*256*1024, b2 + l*256, x);
  }
  lnf_k<<<dim3(BSZ*TSEQ), dim3(64), 0, stream>>>(x, lnf_g, lnf_b, (float*)d_out);
}

// Round 5
// 1760.016 us; speedup vs baseline: 1.1386x; 1.1386x over previous
//
#include <hip/hip_runtime.h>
#include <math.h>

#define NL 10
#define BSZ 2
#define TSEQ 2040
#define TPAD 2048
#define DMOD 256
#define NH 4
#define HDIM 64
#define DFF 1024
#define MPAD (BSZ*TPAD)   // 4096
#define CKV 256           // KV chunk per attention wave-unit

typedef __attribute__((ext_vector_type(8))) short bf16x8;
typedef __attribute__((ext_vector_type(4))) short bf16x4;
typedef __attribute__((ext_vector_type(4))) float f32x4;

__device__ __forceinline__ ushort f2b(float f){
  union { float f; unsigned u; } v; v.f = f;
  unsigned u = v.u;
  return (ushort)((u + 0x7FFFu + ((u >> 16) & 1u)) >> 16);
}
__device__ __forceinline__ float b2f(ushort h){
  union { unsigned u; float f; } v; v.u = ((unsigned)h) << 16; return v.f;
}

// ---- copy sequences (B,2040,256) -> padded x [B][2048][256] f32 ----
__global__ __launch_bounds__(256) void copy_in_k(const float* __restrict__ seq, float* __restrict__ x){
  int idx = blockIdx.x * 256 + threadIdx.x;
  int row = idx >> 6, c = idx & 63;
  if (row >= BSZ * TSEQ) return;
  int b = row / TSEQ, t = row % TSEQ;
  ((float4*)(x + (size_t)(b * TPAD + t) * DMOD))[c] = ((const float4*)(seq + (size_t)row * DMOD))[c];
}

// ---- transpose+cast weights: src (L,K,N) f32 -> dst rows [l][row0+n][k] bf16 ----
__global__ __launch_bounds__(256) void wtrans_k(const float* __restrict__ src, ushort* __restrict__ dst,
                                                int N, int K, int NTOT, int row0, int total){
  int idx = blockIdx.x * 256 + threadIdx.x;
  if (idx >= total) return;
  int kk = idx % K; int rem = idx / K; int n = rem % N; int l = rem / N;
  dst[((size_t)(l * NTOT + row0 + n)) * K + kk] = f2b(src[((size_t)(l * K + kk)) * N + n]);
}

// ---- concat qkv biases ----
__global__ __launch_bounds__(256) void bqkv_k(const float* __restrict__ bq, const float* __restrict__ bk,
                                              const float* __restrict__ bv, float* __restrict__ bqkv){
  int idx = blockIdx.x * 256 + threadIdx.x;
  if (idx >= NL * 768) return;
  int l = idx / 768, n = idx % 768;
  float v = (n < 256) ? bq[l * 256 + n] : ((n < 512) ? bk[l * 256 + n - 256] : bv[l * 256 + n - 512]);
  bqkv[idx] = v;
}

// ---- layernorm: one wave per row, D=256 ----
// MODE 0: rows = MPAD, bf16 out (padded indexing); MODE 1: rows = B*TSEQ, f32 out (compact)
template<int MODE>
__global__ __launch_bounds__(64) void ln_k(const float* __restrict__ x, const float* __restrict__ g,
                                           const float* __restrict__ be, ushort* __restrict__ outb,
                                           float* __restrict__ outf){
  int row = blockIdx.x, lane = threadIdx.x;
  int irow = row;
  if (MODE == 1){ int b = row / TSEQ, t = row % TSEQ; irow = b * TPAD + t; }
  float4 xv = ((const float4*)(x + (size_t)irow * DMOD))[lane];
  float s  = xv.x + xv.y + xv.z + xv.w;
  float s2 = xv.x*xv.x + xv.y*xv.y + xv.z*xv.z + xv.w*xv.w;
  #pragma unroll
  for (int off = 1; off < 64; off <<= 1){ s += __shfl_xor(s, off); s2 += __shfl_xor(s2, off); }
  float mu = s * (1.f/256.f);
  float var = s2 * (1.f/256.f) - mu * mu;
  float rs = rsqrtf(var + 1e-5f);
  float4 gv = ((const float4*)g)[lane];
  float4 bv = ((const float4*)be)[lane];
  float o0 = (xv.x - mu) * rs * gv.x + bv.x;
  float o1 = (xv.y - mu) * rs * gv.y + bv.y;
  float o2 = (xv.z - mu) * rs * gv.z + bv.z;
  float o3 = (xv.w - mu) * rs * gv.w + bv.w;
  if (MODE == 0){
    ushort* o = outb + (size_t)irow * DMOD + lane * 4;
    o[0] = f2b(o0); o[1] = f2b(o1); o[2] = f2b(o2); o[3] = f2b(o3);
  } else {
    float4 ov; ov.x = o0; ov.y = o1; ov.z = o2; ov.w = o3;
    ((float4*)(outf + (size_t)row * DMOD))[lane] = ov;
  }
}

// ---- GEMM: C[M=4096][N] = A[M][K](bf16) * Bt[N][K]^T + bias, fused epilogues ----
// EPI 0: QKV scatter (v stored with per-64 column permutation pi(j)=4*(j&15)+(j>>4))
// EPI 1: residual add into xres; EPI 2: tanh-GELU -> o0 bf16 [M][N]
template<int N, int K, int EPI>
__global__ __launch_bounds__(256) void gemm_k(const ushort* __restrict__ A, const ushort* __restrict__ Bt,
                                              const float* __restrict__ bias, float* __restrict__ xres,
                                              ushort* __restrict__ o0, ushort* __restrict__ o1,
                                              ushort* __restrict__ o2){
  __shared__ ushort Alds[64][72];
  __shared__ ushort Blds[64][72];
  int tid = threadIdx.x;
  int w = tid >> 6, lane = tid & 63;
  int wr = w >> 1, wc = w & 1;
  int l15 = lane & 15, l4 = lane >> 4;
  int row0 = blockIdx.x * 64, col0 = blockIdx.y * 64;
  f32x4 zero = {0.f, 0.f, 0.f, 0.f};
  f32x4 acc[2][2];
  acc[0][0] = zero; acc[0][1] = zero; acc[1][0] = zero; acc[1][1] = zero;
  int r = tid >> 3, c8 = (tid & 7) * 8;
  for (int k0 = 0; k0 < K; k0 += 64){
    #pragma unroll
    for (int it = 0; it < 2; ++it){
      int rr = r + it * 32;
      *(bf16x8*)&Alds[rr][c8] = *(const bf16x8*)(A  + (size_t)(row0 + rr) * K + k0 + c8);
      *(bf16x8*)&Blds[rr][c8] = *(const bf16x8*)(Bt + (size_t)(col0 + rr) * K + k0 + c8);
    }
    __syncthreads();
    #pragma unroll
    for (int ks = 0; ks < 2; ++ks){
      bf16x8 af[2], bfr[2];
      #pragma unroll
      for (int i = 0; i < 2; ++i){
        af[i]  = *(const bf16x8*)&Alds[wr * 32 + i * 16 + l15][ks * 32 + l4 * 8];
        bfr[i] = *(const bf16x8*)&Blds[wc * 32 + i * 16 + l15][ks * 32 + l4 * 8];
      }
      #pragma unroll
      for (int mr = 0; mr < 2; ++mr)
        #pragma unroll
        for (int nc = 0; nc < 2; ++nc)
          acc[mr][nc] = __builtin_amdgcn_mfma_f32_16x16x32_bf16(af[mr], bfr[nc], acc[mr][nc], 0, 0, 0);
    }
    __syncthreads();
  }
  #pragma unroll
  for (int mr = 0; mr < 2; ++mr){
    #pragma unroll
    for (int nc = 0; nc < 2; ++nc){
      #pragma unroll
      for (int rr = 0; rr < 4; ++rr){
        int m = row0 + wr * 32 + mr * 16 + l4 * 4 + rr;
        int n = col0 + wc * 32 + nc * 16 + l15;
        float v = acc[mr][nc][rr] + bias[n];
        if (EPI == 0){
          int b = m >> 11, t = m & 2047;
          int which = n >> 8, hn = n & 255, hh = hn >> 6, hd = hn & 63;
          if (which == 0)      o0[(((size_t)(b * NH + hh)) * TPAD + t) * HDIM + hd] = f2b(v);
          else if (which == 1) o1[(((size_t)(b * NH + hh)) * TPAD + t) * HDIM + hd] = f2b(v);
          else {
            int tp = (t & ~63) | (((t & 15) << 2) | ((t >> 4) & 3));   // pi within 64-tile
            o2[(((size_t)(b * NH + hh)) * HDIM + hd) * TPAD + tp] = f2b(v);
          }
        } else if (EPI == 1){
          xres[(size_t)m * 256 + n] += v;
        } else {
          float uu = 0.7978845608028654f * (v + 0.044715f * v * v * v);
          float e = __expf(2.f * uu);
          float th = 1.f - 2.f / (e + 1.f);
          o0[(size_t)m * N + n] = f2b(0.5f * v * (1.f + th));
        }
      }
    }
  }
}

// ---- split-KV flash attention: batched single-pass softmax per 256-KV chunk ----
// unit u = (bh<<10)|(qt<<3)|ch ; grid 2048 blocks x 4 waves = 8192 units.
__global__ __launch_bounds__(256) void attn_part_k(const ushort* __restrict__ qq, const ushort* __restrict__ kkk,
                                                   const ushort* __restrict__ vt,
                                                   ushort* __restrict__ po, float* __restrict__ pml){
  __shared__ ushort Plds[4][16][264];
  int tid = threadIdx.x, w = tid >> 6, lane = tid & 63;
  int l15 = lane & 15, l4 = lane >> 4;
  int u = blockIdx.x * 4 + w;
  int bh = u >> 10, qt = (u >> 3) & 127, ch = u & 7;
  int i0 = qt * 16;
  int je = ((i0 + 15) / 17) * 17 + 17; je = je < TSEQ ? je : TSEQ;
  int jstart = ch * CKV;
  if (jstart >= je) return;
  int jend_w = (jstart + CKV) < je ? (jstart + CKV) : je;

  const ushort* qb = qq  + (size_t)bh * TPAD * HDIM;
  const ushort* kb = kkk + (size_t)bh * TPAD * HDIM;
  const ushort* vb = vt  + (size_t)bh * HDIM * TPAD;

  int qrow = i0 + l15;
  bf16x8 aq0 = *(const bf16x8*)(qb + (size_t)qrow * HDIM + l4 * 8);
  bf16x8 aq1 = *(const bf16x8*)(qb + (size_t)qrow * HDIM + 32 + l4 * 8);

  f32x4 zero = {0.f, 0.f, 0.f, 0.f};
  f32x4 s[4][4];
  bool pres[4];
  // ---- QK^T for all tiles in chunk ----
  #pragma unroll
  for (int jt = 0; jt < 4; ++jt){
    int j0 = jstart + jt * 64;
    pres[jt] = (j0 < jend_w);
    if (pres[jt]){
      #pragma unroll
      for (int f = 0; f < 4; ++f) s[jt][f] = zero;
      #pragma unroll
      for (int f = 0; f < 4; ++f){
        bf16x8 kf = *(const bf16x8*)(kb + (size_t)(j0 + f * 16 + l15) * HDIM + l4 * 8);
        s[jt][f] = __builtin_amdgcn_mfma_f32_16x16x32_bf16(aq0, kf, s[jt][f], 0, 0, 0);
      }
      #pragma unroll
      for (int f = 0; f < 4; ++f){
        bf16x8 kf = *(const bf16x8*)(kb + (size_t)(j0 + f * 16 + l15) * HDIM + 32 + l4 * 8);
        s[jt][f] = __builtin_amdgcn_mfma_f32_16x16x32_bf16(aq1, kf, s[jt][f], 0, 0, 0);
      }
    }
  }
  // ---- mask + scale + batched max ----
  int ig0 = i0 + l4 * 4;
  int igv[4], iblk[4];
  float mx[4];
  #pragma unroll
  for (int rr = 0; rr < 4; ++rr){
    igv[rr] = ig0 + rr;
    iblk[rr] = (int)((unsigned)(ig0 + rr) / 17u);
    mx[rr] = -1e30f;
  }
  #pragma unroll
  for (int jt = 0; jt < 4; ++jt){
    if (!pres[jt]) continue;
    int j0 = jstart + jt * 64;
    #pragma unroll
    for (int f = 0; f < 4; ++f){
      int jg = j0 + f * 16 + l15;
      int jb = (int)((unsigned)jg / 17u);
      #pragma unroll
      for (int rr = 0; rr < 4; ++rr){
        float sv = s[jt][f][rr] * 0.125f;
        bool ok = (jg <= igv[rr]) || (jb == iblk[rr]);
        sv = ok ? sv : -1e30f;
        s[jt][f][rr] = sv;
        mx[rr] = fmaxf(mx[rr], sv);
      }
    }
  }
  #pragma unroll
  for (int off = 1; off < 16; off <<= 1){
    #pragma unroll
    for (int rr = 0; rr < 4; ++rr) mx[rr] = fmaxf(mx[rr], __shfl_xor(mx[rr], off));
  }
  // ---- exp + packed P store (column-permuted) + batched sum ----
  float ps[4] = {0.f, 0.f, 0.f, 0.f};
  #pragma unroll
  for (int jt = 0; jt < 4; ++jt){
    if (!pres[jt]) continue;
    #pragma unroll
    for (int rr = 0; rr < 4; ++rr){
      bf16x4 pk;
      #pragma unroll
      for (int f = 0; f < 4; ++f){
        float p = __expf(s[jt][f][rr] - mx[rr]);
        ps[rr] += p;
        pk[f] = (short)f2b(p);
      }
      *(bf16x4*)&Plds[w][l4 * 4 + rr][jt * 64 + l15 * 4] = pk;
    }
  }
  #pragma unroll
  for (int off = 1; off < 16; off <<= 1){
    #pragma unroll
    for (int rr = 0; rr < 4; ++rr) ps[rr] += __shfl_xor(ps[rr], off);
  }
  // ---- PV (V pre-permuted to match P's column order) ----
  f32x4 o_[4];
  o_[0] = zero; o_[1] = zero; o_[2] = zero; o_[3] = zero;
  #pragma unroll
  for (int jt = 0; jt < 4; ++jt){
    if (!pres[jt]) continue;
    int j0 = jstart + jt * 64;
    #pragma unroll
    for (int ks = 0; ks < 2; ++ks){
      bf16x8 pf = *(const bf16x8*)&Plds[w][l15][jt * 64 + ks * 32 + l4 * 8];
      #pragma unroll
      for (int f = 0; f < 4; ++f){
        bf16x8 vf = *(const bf16x8*)(vb + (size_t)(f * 16 + l15) * TPAD + j0 + ks * 32 + l4 * 8);
        o_[f] = __builtin_amdgcn_mfma_f32_16x16x32_bf16(pf, vf, o_[f], 0, 0, 0);
      }
    }
  }
  // ---- write partials: po[u][16][64] bf16, pml[u][16][2] f32 ----
  size_t ob = (size_t)u * 1024;
  #pragma unroll
  for (int rr = 0; rr < 4; ++rr){
    int r16 = l4 * 4 + rr;
    #pragma unroll
    for (int f = 0; f < 4; ++f)
      po[ob + r16 * 64 + f * 16 + l15] = f2b(o_[f][rr]);
    if (l15 == 0){
      pml[(size_t)u * 32 + r16 * 2 + 0] = mx[rr];
      pml[(size_t)u * 32 + r16 * 2 + 1] = ps[rr];
    }
  }
}

// ---- merge partials -> y bf16 [b][t pad][D] ----
__global__ __launch_bounds__(64) void attn_merge_k(const ushort* __restrict__ po, const float* __restrict__ pml,
                                                   ushort* __restrict__ y){
  int qt = blockIdx.x, bh = blockIdx.y;
  int b = bh >> 2, hh = bh & 3;
  int d = threadIdx.x;
  int i0 = qt * 16;
  int je = ((i0 + 15) / 17) * 17 + 17; je = je < TSEQ ? je : TSEQ;
  int nch = (je + CKV - 1) / CKV;
  int u0 = ((bh << 7) + qt) << 3;
  for (int r = 0; r < 16; ++r){
    float mg = -1e30f;
    for (int ch = 0; ch < nch; ++ch)
      mg = fmaxf(mg, pml[(size_t)(u0 + ch) * 32 + r * 2]);
    float lg = 0.f, o = 0.f;
    for (int ch = 0; ch < nch; ++ch){
      float mm = pml[(size_t)(u0 + ch) * 32 + r * 2];
      float ll = pml[(size_t)(u0 + ch) * 32 + r * 2 + 1];
      float a = __expf(mm - mg);
      lg += a * ll;
      o  += a * b2f(po[(size_t)(u0 + ch) * 1024 + r * 64 + d]);
    }
    y[((size_t)(b * TPAD + i0 + r)) * DMOD + hh * HDIM + d] = f2b(o / lg);
  }
}

extern "C" void kernel_launch(void* const* d_in, const int* in_sizes, int n_in,
                              void* d_out, int out_size, void* d_ws, size_t ws_size,
                              hipStream_t stream){
  const float* seq    = (const float*)d_in[0];
  const float* ln1_g  = (const float*)d_in[1];
  const float* ln1_b  = (const float*)d_in[2];
  const float* wq     = (const float*)d_in[3];
  const float* bq     = (const float*)d_in[4];
  const float* wk     = (const float*)d_in[5];
  const float* bk     = (const float*)d_in[6];
  const float* wv     = (const float*)d_in[7];
  const float* bv     = (const float*)d_in[8];
  const float* wproj  = (const float*)d_in[9];
  const float* bproj  = (const float*)d_in[10];
  const float* ln2_g  = (const float*)d_in[11];
  const float* ln2_b  = (const float*)d_in[12];
  const float* w1     = (const float*)d_in[13];
  const float* b1     = (const float*)d_in[14];
  const float* w2     = (const float*)d_in[15];
  const float* b2     = (const float*)d_in[16];
  const float* lnf_g  = (const float*)d_in[17];
  const float* lnf_b  = (const float*)d_in[18];

  size_t off = 0;
  char* base = (char*)d_ws;
  auto carve = [&](size_t bytes) -> void* {
    void* p = base + off;
    off += (bytes + 255) & ~(size_t)255;
    return p;
  };
  float*  x      = (float*) carve((size_t)MPAD * DMOD * 4);
  ushort* h      = (ushort*)carve((size_t)MPAD * DMOD * 2);
  ushort* qbuf   = (ushort*)carve((size_t)BSZ * NH * TPAD * HDIM * 2);
  ushort* kbuf   = (ushort*)carve((size_t)BSZ * NH * TPAD * HDIM * 2);
  ushort* vtbuf  = (ushort*)carve((size_t)BSZ * NH * TPAD * HDIM * 2);
  ushort* ybuf   = (ushort*)carve((size_t)MPAD * DMOD * 2);
  ushort* mid    = (ushort*)carve((size_t)MPAD * DFF * 2);
  ushort* wqkvT  = (ushort*)carve((size_t)NL * 768 * 256 * 2);
  ushort* wprojT = (ushort*)carve((size_t)NL * 256 * 256 * 2);
  ushort* w1T    = (ushort*)carve((size_t)NL * 1024 * 256 * 2);
  ushort* w2T    = (ushort*)carve((size_t)NL * 256 * 1024 * 2);
  float*  bqkv   = (float*) carve((size_t)NL * 768 * 4);
  ushort* po     = (ushort*)carve((size_t)8192 * 1024 * 2);
  float*  pml    = (float*) carve((size_t)8192 * 32 * 4);
  if (off > ws_size) return;  // workspace too small; bail

  // input copy + weight prep
  copy_in_k<<<dim3((BSZ*TSEQ*64 + 255)/256), dim3(256), 0, stream>>>(seq, x);
  int tot;
  tot = NL*256*256;  wtrans_k<<<dim3((tot+255)/256), dim3(256), 0, stream>>>(wq,    wqkvT,  256, 256,  768, 0,   tot);
  tot = NL*256*256;  wtrans_k<<<dim3((tot+255)/256), dim3(256), 0, stream>>>(wk,    wqkvT,  256, 256,  768, 256, tot);
  tot = NL*256*256;  wtrans_k<<<dim3((tot+255)/256), dim3(256), 0, stream>>>(wv,    wqkvT,  256, 256,  768, 512, tot);
  tot = NL*256*256;  wtrans_k<<<dim3((tot+255)/256), dim3(256), 0, stream>>>(wproj, wprojT, 256, 256,  256, 0,   tot);
  tot = NL*1024*256; wtrans_k<<<dim3((tot+255)/256), dim3(256), 0, stream>>>(w1,    w1T,   1024, 256, 1024, 0,   tot);
  tot = NL*256*1024; wtrans_k<<<dim3((tot+255)/256), dim3(256), 0, stream>>>(w2,    w2T,    256,1024,  256, 0,   tot);
  bqkv_k<<<dim3((NL*768 + 255)/256), dim3(256), 0, stream>>>(bq, bk, bv, bqkv);

  for (int l = 0; l < NL; ++l){
    ln_k<0><<<dim3(MPAD), dim3(64), 0, stream>>>(x, ln1_g + l*256, ln1_b + l*256, h, nullptr);
    gemm_k<768,256,0><<<dim3(64,12), dim3(256), 0, stream>>>(
        h, wqkvT + (size_t)l*768*256, bqkv + l*768, nullptr, qbuf, kbuf, vtbuf);
    attn_part_k<<<dim3(2048), dim3(256), 0, stream>>>(qbuf, kbuf, vtbuf, po, pml);
    attn_merge_k<<<dim3(128, 8), dim3(64), 0, stream>>>(po, pml, ybuf);
    gemm_k<256,256,1><<<dim3(64,4), dim3(256), 0, stream>>>(
        ybuf, wprojT + (size_t)l*256*256, bproj + l*256, x, nullptr, nullptr, nullptr);
    ln_k<0><<<dim3(MPAD), dim3(64), 0, stream>>>(x, ln2_g + l*256, ln2_b + l*256, h, nullptr);
    gemm_k<1024,256,2><<<dim3(64,16), dim3(256), 0, stream>>>(
        h, w1T + (size_t)l*1024*256, b1 + l*1024, nullptr, mid, nullptr, nullptr);
    gemm_k<256,1024,1><<<dim3(64,4), dim3(256), 0, stream>>>(
        mid, w2T + (size_t)l*256*1024, b2 + l*256, x, nullptr, nullptr, nullptr);
  }
  ln_k<1><<<dim3(BSZ*TSEQ), dim3(64), 0, stream>>>(x, lnf_g, lnf_b, nullptr, (float*)d_out);
}

// Round 6
// 1221.833 us; speedup vs baseline: 1.6401x; 1.4405x over previous
//
#include <hip/hip_runtime.h>
#include <math.h>

#define NL 10
#define BSZ 2
#define TSEQ 2040
#define TPAD 2048
#define DMOD 256
#define NH 4
#define HDIM 64
#define DFF 1024
#define MPAD (BSZ*TPAD)   // 4096
#define CKV 512           // KV chunk per attention block

typedef __attribute__((ext_vector_type(8))) short bf16x8;
typedef __attribute__((ext_vector_type(4))) short bf16x4;
typedef __attribute__((ext_vector_type(4))) float f32x4;

__device__ __forceinline__ ushort f2b(float f){
  union { float f; unsigned u; } v; v.f = f;
  unsigned u = v.u;
  return (ushort)((u + 0x7FFFu + ((u >> 16) & 1u)) >> 16);
}
__device__ __forceinline__ float b2f(ushort h){
  union { unsigned u; float f; } v; v.u = ((unsigned)h) << 16; return v.f;
}

// ---- copy sequences (B,2040,256) -> padded x [B][2048][256] f32 ----
__global__ __launch_bounds__(256) void copy_in_k(const float* __restrict__ seq, float* __restrict__ x){
  int idx = blockIdx.x * 256 + threadIdx.x;
  int row = idx >> 6, c = idx & 63;
  if (row >= BSZ * TSEQ) return;
  int b = row / TSEQ, t = row % TSEQ;
  ((float4*)(x + (size_t)(b * TPAD + t) * DMOD))[c] = ((const float4*)(seq + (size_t)row * DMOD))[c];
}

// ---- transpose+cast weights: src (L,K,N) f32 -> dst rows [l][row0+n][k] bf16 ----
__global__ __launch_bounds__(256) void wtrans_k(const float* __restrict__ src, ushort* __restrict__ dst,
                                                int N, int K, int NTOT, int row0, int total){
  int idx = blockIdx.x * 256 + threadIdx.x;
  if (idx >= total) return;
  int kk = idx % K; int rem = idx / K; int n = rem % N; int l = rem / N;
  dst[((size_t)(l * NTOT + row0 + n)) * K + kk] = f2b(src[((size_t)(l * K + kk)) * N + n]);
}

// ---- concat qkv biases ----
__global__ __launch_bounds__(256) void bqkv_k(const float* __restrict__ bq, const float* __restrict__ bk,
                                              const float* __restrict__ bv, float* __restrict__ bqkv){
  int idx = blockIdx.x * 256 + threadIdx.x;
  if (idx >= NL * 768) return;
  int l = idx / 768, n = idx % 768;
  float v = (n < 256) ? bq[l * 256 + n] : ((n < 512) ? bk[l * 256 + n - 256] : bv[l * 256 + n - 512]);
  bqkv[idx] = v;
}

// ---- layernorm: one wave per row, D=256 ----
// MODE 0: rows = MPAD, bf16 out (padded indexing); MODE 1: rows = B*TSEQ, f32 out (compact)
template<int MODE>
__global__ __launch_bounds__(64) void ln_k(const float* __restrict__ x, const float* __restrict__ g,
                                           const float* __restrict__ be, ushort* __restrict__ outb,
                                           float* __restrict__ outf){
  int row = blockIdx.x, lane = threadIdx.x;
  int irow = row;
  if (MODE == 1){ int b = row / TSEQ, t = row % TSEQ; irow = b * TPAD + t; }
  float4 xv = ((const float4*)(x + (size_t)irow * DMOD))[lane];
  float s  = xv.x + xv.y + xv.z + xv.w;
  float s2 = xv.x*xv.x + xv.y*xv.y + xv.z*xv.z + xv.w*xv.w;
  #pragma unroll
  for (int off = 1; off < 64; off <<= 1){ s += __shfl_xor(s, off); s2 += __shfl_xor(s2, off); }
  float mu = s * (1.f/256.f);
  float var = s2 * (1.f/256.f) - mu * mu;
  float rs = rsqrtf(var + 1e-5f);
  float4 gv = ((const float4*)g)[lane];
  float4 bv = ((const float4*)be)[lane];
  float o0 = (xv.x - mu) * rs * gv.x + bv.x;
  float o1 = (xv.y - mu) * rs * gv.y + bv.y;
  float o2 = (xv.z - mu) * rs * gv.z + bv.z;
  float o3 = (xv.w - mu) * rs * gv.w + bv.w;
  if (MODE == 0){
    ushort* o = outb + (size_t)irow * DMOD + lane * 4;
    o[0] = f2b(o0); o[1] = f2b(o1); o[2] = f2b(o2); o[3] = f2b(o3);
  } else {
    float4 ov; ov.x = o0; ov.y = o1; ov.z = o2; ov.w = o3;
    ((float4*)(outf + (size_t)row * DMOD))[lane] = ov;
  }
}

// ---- GEMM: C[M=4096][N] = A[M][K](bf16) * Bt[N][K]^T + bias, fused epilogues ----
// EPI 0: QKV scatter (v stored with per-64 column permutation pi(j)=4*(j&15)+(j>>4))
// EPI 1: residual add into xres; EPI 2: tanh-GELU -> o0 bf16 [M][N]
template<int N, int K, int EPI>
__global__ __launch_bounds__(256) void gemm_k(const ushort* __restrict__ A, const ushort* __restrict__ Bt,
                                              const float* __restrict__ bias, float* __restrict__ xres,
                                              ushort* __restrict__ o0, ushort* __restrict__ o1,
                                              ushort* __restrict__ o2){
  __shared__ ushort Alds[64][72];
  __shared__ ushort Blds[64][72];
  int tid = threadIdx.x;
  int w = tid >> 6, lane = tid & 63;
  int wr = w >> 1, wc = w & 1;
  int l15 = lane & 15, l4 = lane >> 4;
  int row0 = blockIdx.x * 64, col0 = blockIdx.y * 64;
  f32x4 zero = {0.f, 0.f, 0.f, 0.f};
  f32x4 acc[2][2];
  acc[0][0] = zero; acc[0][1] = zero; acc[1][0] = zero; acc[1][1] = zero;
  int r = tid >> 3, c8 = (tid & 7) * 8;
  for (int k0 = 0; k0 < K; k0 += 64){
    #pragma unroll
    for (int it = 0; it < 2; ++it){
      int rr = r + it * 32;
      *(bf16x8*)&Alds[rr][c8] = *(const bf16x8*)(A  + (size_t)(row0 + rr) * K + k0 + c8);
      *(bf16x8*)&Blds[rr][c8] = *(const bf16x8*)(Bt + (size_t)(col0 + rr) * K + k0 + c8);
    }
    __syncthreads();
    #pragma unroll
    for (int ks = 0; ks < 2; ++ks){
      bf16x8 af[2], bfr[2];
      #pragma unroll
      for (int i = 0; i < 2; ++i){
        af[i]  = *(const bf16x8*)&Alds[wr * 32 + i * 16 + l15][ks * 32 + l4 * 8];
        bfr[i] = *(const bf16x8*)&Blds[wc * 32 + i * 16 + l15][ks * 32 + l4 * 8];
      }
      #pragma unroll
      for (int mr = 0; mr < 2; ++mr)
        #pragma unroll
        for (int nc = 0; nc < 2; ++nc)
          acc[mr][nc] = __builtin_amdgcn_mfma_f32_16x16x32_bf16(af[mr], bfr[nc], acc[mr][nc], 0, 0, 0);
    }
    __syncthreads();
  }
  #pragma unroll
  for (int mr = 0; mr < 2; ++mr){
    #pragma unroll
    for (int nc = 0; nc < 2; ++nc){
      #pragma unroll
      for (int rr = 0; rr < 4; ++rr){
        int m = row0 + wr * 32 + mr * 16 + l4 * 4 + rr;
        int n = col0 + wc * 32 + nc * 16 + l15;
        float v = acc[mr][nc][rr] + bias[n];
        if (EPI == 0){
          int b = m >> 11, t = m & 2047;
          int which = n >> 8, hn = n & 255, hh = hn >> 6, hd = hn & 63;
          if (which == 0)      o0[(((size_t)(b * NH + hh)) * TPAD + t) * HDIM + hd] = f2b(v);
          else if (which == 1) o1[(((size_t)(b * NH + hh)) * TPAD + t) * HDIM + hd] = f2b(v);
          else {
            int tp = (t & ~63) | (((t & 15) << 2) | ((t >> 4) & 3));   // pi within 64-tile
            o2[(((size_t)(b * NH + hh)) * HDIM + hd) * TPAD + tp] = f2b(v);
          }
        } else if (EPI == 1){
          xres[(size_t)m * 256 + n] += v;
        } else {
          float uu = 0.7978845608028654f * (v + 0.044715f * v * v * v);
          float e = __expf(2.f * uu);
          float th = 1.f - 2.f / (e + 1.f);
          o0[(size_t)m * N + n] = f2b(0.5f * v * (1.f + th));
        }
      }
    }
  }
}

// ---- split-KV flash attention with LDS-staged K/V shared across 4 waves ----
// block = (qg 64 q-rows, ch 512-KV chunk, bh); grid (32,4,8); 4 waves.
__global__ __launch_bounds__(256) void attn_tile_k(const ushort* __restrict__ qq, const ushort* __restrict__ kkk,
                                                   const ushort* __restrict__ vt,
                                                   ushort* __restrict__ po, float* __restrict__ pml){
  __shared__ ushort Klds[64][72];
  __shared__ ushort Vlds[64][72];
  __shared__ ushort Plds[4][16][72];
  int tid = threadIdx.x, w = tid >> 6, lane = tid & 63;
  int l15 = lane & 15, l4 = lane >> 4;
  int qg = blockIdx.x, ch = blockIdx.y, bh = blockIdx.z;
  int r0 = qg * 64;
  int je_blk = ((r0 + 63) / 17 + 1) * 17; je_blk = je_blk < TSEQ ? je_blk : TSEQ;
  int jstart = ch * CKV;
  if (jstart >= je_blk) return;                       // idle block (uniform)
  int jend = (jstart + CKV) < je_blk ? (jstart + CKV) : je_blk;

  int i0 = r0 + w * 16;
  int je_w = ((i0 + 15) / 17 + 1) * 17; je_w = je_w < TSEQ ? je_w : TSEQ;

  const ushort* qb = qq  + (size_t)bh * TPAD * HDIM;
  const ushort* kb = kkk + (size_t)bh * TPAD * HDIM;
  const ushort* vb = vt  + (size_t)bh * HDIM * TPAD;

  bf16x8 aq0 = *(const bf16x8*)(qb + (size_t)(i0 + l15) * HDIM + l4 * 8);
  bf16x8 aq1 = *(const bf16x8*)(qb + (size_t)(i0 + l15) * HDIM + 32 + l4 * 8);

  f32x4 zero = {0.f, 0.f, 0.f, 0.f};
  float m_[4], l_[4];
  f32x4 o_[4];
  #pragma unroll
  for (int i = 0; i < 4; ++i){ m_[i] = -1e30f; l_[i] = 0.f; o_[i] = zero; }

  int sr = tid >> 2, sc = (tid & 3) * 16;   // staging: 4 threads/row, 32B each
  for (int j0 = jstart; j0 < jend; j0 += 64){
    __syncthreads();                        // prev compute done before overwrite
    *(bf16x8*)&Klds[sr][sc]     = *(const bf16x8*)(kb + (size_t)(j0 + sr) * HDIM + sc);
    *(bf16x8*)&Klds[sr][sc + 8] = *(const bf16x8*)(kb + (size_t)(j0 + sr) * HDIM + sc + 8);
    *(bf16x8*)&Vlds[sr][sc]     = *(const bf16x8*)(vb + (size_t)sr * TPAD + j0 + sc);
    *(bf16x8*)&Vlds[sr][sc + 8] = *(const bf16x8*)(vb + (size_t)sr * TPAD + j0 + sc + 8);
    __syncthreads();
    if (j0 >= je_w) continue;               // fully masked for this wave (barriers already passed)
    // ---- QK^T from LDS ----
    f32x4 s[4];
    s[0] = zero; s[1] = zero; s[2] = zero; s[3] = zero;
    #pragma unroll
    for (int f = 0; f < 4; ++f){
      bf16x8 kf = *(const bf16x8*)&Klds[f * 16 + l15][l4 * 8];
      s[f] = __builtin_amdgcn_mfma_f32_16x16x32_bf16(aq0, kf, s[f], 0, 0, 0);
    }
    #pragma unroll
    for (int f = 0; f < 4; ++f){
      bf16x8 kf = *(const bf16x8*)&Klds[f * 16 + l15][32 + l4 * 8];
      s[f] = __builtin_amdgcn_mfma_f32_16x16x32_bf16(aq1, kf, s[f], 0, 0, 0);
    }
    // ---- mask + scale + online softmax ----
    #pragma unroll
    for (int rr = 0; rr < 4; ++rr){
      int ig = i0 + l4 * 4 + rr;
      int ib = (int)((unsigned)ig / 17u);
      float mx = -1e30f;
      #pragma unroll
      for (int f = 0; f < 4; ++f){
        int jg = j0 + f * 16 + l15;
        int jb = (int)((unsigned)jg / 17u);
        float sv = s[f][rr] * 0.125f;
        bool ok = (jg <= ig) || (jb == ib);
        sv = ok ? sv : -1e30f;
        s[f][rr] = sv;
        mx = fmaxf(mx, sv);
      }
      #pragma unroll
      for (int off = 1; off < 16; off <<= 1) mx = fmaxf(mx, __shfl_xor(mx, off));
      float mn = fmaxf(m_[rr], mx);
      float alpha = __expf(m_[rr] - mn);
      float ps = 0.f;
      bf16x4 pk;
      #pragma unroll
      for (int f = 0; f < 4; ++f){
        float p = __expf(s[f][rr] - mn);
        ps += p;
        pk[f] = (short)f2b(p);
      }
      *(bf16x4*)&Plds[w][l4 * 4 + rr][l15 * 4] = pk;
      #pragma unroll
      for (int off = 1; off < 16; off <<= 1) ps += __shfl_xor(ps, off);
      l_[rr] = l_[rr] * alpha + ps;
      m_[rr] = mn;
      #pragma unroll
      for (int f = 0; f < 4; ++f) o_[f][rr] *= alpha;
    }
    // ---- PV (P pi-packed; V pre-permuted in global to match) ----
    #pragma unroll
    for (int ks = 0; ks < 2; ++ks){
      bf16x8 pf = *(const bf16x8*)&Plds[w][l15][ks * 32 + l4 * 8];
      #pragma unroll
      for (int f = 0; f < 4; ++f){
        bf16x8 vf = *(const bf16x8*)&Vlds[f * 16 + l15][ks * 32 + l4 * 8];
        o_[f] = __builtin_amdgcn_mfma_f32_16x16x32_bf16(pf, vf, o_[f], 0, 0, 0);
      }
    }
  }
  // ---- write partials: u = (bh*128 + qt)*4 + ch ----
  int qt = qg * 4 + w;
  int u = ((bh << 7) + qt) * 4 + ch;
  size_t ob = (size_t)u * 1024;
  #pragma unroll
  for (int rr = 0; rr < 4; ++rr){
    int r16 = l4 * 4 + rr;
    #pragma unroll
    for (int f = 0; f < 4; ++f)
      po[ob + r16 * 64 + f * 16 + l15] = f2b(o_[f][rr]);
    if (l15 == 0){
      pml[(size_t)u * 32 + r16 * 2 + 0] = m_[rr];
      pml[(size_t)u * 32 + r16 * 2 + 1] = l_[rr];
    }
  }
}

// ---- merge partials -> y bf16 [b][t pad][D] ----
__global__ __launch_bounds__(64) void attn_merge_k(const ushort* __restrict__ po, const float* __restrict__ pml,
                                                   ushort* __restrict__ y){
  int qt = blockIdx.x, bh = blockIdx.y;
  int b = bh >> 2, hh = bh & 3;
  int d = threadIdx.x;
  int i0 = qt * 16;
  int je = ((i0 + 15) / 17) * 17 + 17; je = je < TSEQ ? je : TSEQ;
  int nch = (je + CKV - 1) / CKV;
  int u0 = ((bh << 7) + qt) << 2;
  for (int r = 0; r < 16; ++r){
    float mg = -1e30f;
    for (int ch = 0; ch < nch; ++ch)
      mg = fmaxf(mg, pml[(size_t)(u0 + ch) * 32 + r * 2]);
    float lg = 0.f, o = 0.f;
    for (int ch = 0; ch < nch; ++ch){
      float mm = pml[(size_t)(u0 + ch) * 32 + r * 2];
      float ll = pml[(size_t)(u0 + ch) * 32 + r * 2 + 1];
      float a = __expf(mm - mg);
      lg += a * ll;
      o  += a * b2f(po[(size_t)(u0 + ch) * 1024 + r * 64 + d]);
    }
    y[((size_t)(b * TPAD + i0 + r)) * DMOD + hh * HDIM + d] = f2b(o / lg);
  }
}

extern "C" void kernel_launch(void* const* d_in, const int* in_sizes, int n_in,
                              void* d_out, int out_size, void* d_ws, size_t ws_size,
                              hipStream_t stream){
  const float* seq    = (const float*)d_in[0];
  const float* ln1_g  = (const float*)d_in[1];
  const float* ln1_b  = (const float*)d_in[2];
  const float* wq     = (const float*)d_in[3];
  const float* bq     = (const float*)d_in[4];
  const float* wk     = (const float*)d_in[5];
  const float* bk     = (const float*)d_in[6];
  const float* wv     = (const float*)d_in[7];
  const float* bv     = (const float*)d_in[8];
  const float* wproj  = (const float*)d_in[9];
  const float* bproj  = (const float*)d_in[10];
  const float* ln2_g  = (const float*)d_in[11];
  const float* ln2_b  = (const float*)d_in[12];
  const float* w1     = (const float*)d_in[13];
  const float* b1     = (const float*)d_in[14];
  const float* w2     = (const float*)d_in[15];
  const float* b2     = (const float*)d_in[16];
  const float* lnf_g  = (const float*)d_in[17];
  const float* lnf_b  = (const float*)d_in[18];

  size_t off = 0;
  char* base = (char*)d_ws;
  auto carve = [&](size_t bytes) -> void* {
    void* p = base + off;
    off += (bytes + 255) & ~(size_t)255;
    return p;
  };
  float*  x      = (float*) carve((size_t)MPAD * DMOD * 4);
  ushort* h      = (ushort*)carve((size_t)MPAD * DMOD * 2);
  ushort* qbuf   = (ushort*)carve((size_t)BSZ * NH * TPAD * HDIM * 2);
  ushort* kbuf   = (ushort*)carve((size_t)BSZ * NH * TPAD * HDIM * 2);
  ushort* vtbuf  = (ushort*)carve((size_t)BSZ * NH * TPAD * HDIM * 2);
  ushort* ybuf   = (ushort*)carve((size_t)MPAD * DMOD * 2);
  ushort* mid    = (ushort*)carve((size_t)MPAD * DFF * 2);
  ushort* wqkvT  = (ushort*)carve((size_t)NL * 768 * 256 * 2);
  ushort* wprojT = (ushort*)carve((size_t)NL * 256 * 256 * 2);
  ushort* w1T    = (ushort*)carve((size_t)NL * 1024 * 256 * 2);
  ushort* w2T    = (ushort*)carve((size_t)NL * 256 * 1024 * 2);
  float*  bqkv   = (float*) carve((size_t)NL * 768 * 4);
  ushort* po     = (ushort*)carve((size_t)4096 * 1024 * 2);
  float*  pml    = (float*) carve((size_t)4096 * 32 * 4);
  if (off > ws_size) return;  // workspace too small; bail

  // input copy + weight prep
  copy_in_k<<<dim3((BSZ*TSEQ*64 + 255)/256), dim3(256), 0, stream>>>(seq, x);
  int tot;
  tot = NL*256*256;  wtrans_k<<<dim3((tot+255)/256), dim3(256), 0, stream>>>(wq,    wqkvT,  256, 256,  768, 0,   tot);
  tot = NL*256*256;  wtrans_k<<<dim3((tot+255)/256), dim3(256), 0, stream>>>(wk,    wqkvT,  256, 256,  768, 256, tot);
  tot = NL*256*256;  wtrans_k<<<dim3((tot+255)/256), dim3(256), 0, stream>>>(wv,    wqkvT,  256, 256,  768, 512, tot);
  tot = NL*256*256;  wtrans_k<<<dim3((tot+255)/256), dim3(256), 0, stream>>>(wproj, wprojT, 256, 256,  256, 0,   tot);
  tot = NL*1024*256; wtrans_k<<<dim3((tot+255)/256), dim3(256), 0, stream>>>(w1,    w1T,   1024, 256, 1024, 0,   tot);
  tot = NL*256*1024; wtrans_k<<<dim3((tot+255)/256), dim3(256), 0, stream>>>(w2,    w2T,    256,1024,  256, 0,   tot);
  bqkv_k<<<dim3((NL*768 + 255)/256), dim3(256), 0, stream>>>(bq, bk, bv, bqkv);

  for (int l = 0; l < NL; ++l){
    ln_k<0><<<dim3(MPAD), dim3(64), 0, stream>>>(x, ln1_g + l*256, ln1_b + l*256, h, nullptr);
    gemm_k<768,256,0><<<dim3(64,12), dim3(256), 0, stream>>>(
        h, wqkvT + (size_t)l*768*256, bqkv + l*768, nullptr, qbuf, kbuf, vtbuf);
    attn_tile_k<<<dim3(32,4,8), dim3(256), 0, stream>>>(qbuf, kbuf, vtbuf, po, pml);
    attn_merge_k<<<dim3(128, 8), dim3(64), 0, stream>>>(po, pml, ybuf);
    gemm_k<256,256,1><<<dim3(64,4), dim3(256), 0, stream>>>(
        ybuf, wprojT + (size_t)l*256*256, bproj + l*256, x, nullptr, nullptr, nullptr);
    ln_k<0><<<dim3(MPAD), dim3(64), 0, stream>>>(x, ln2_g + l*256, ln2_b + l*256, h, nullptr);
    gemm_k<1024,256,2><<<dim3(64,16), dim3(256), 0, stream>>>(
        h, w1T + (size_t)l*1024*256, b1 + l*1024, nullptr, mid, nullptr, nullptr);
    gemm_k<256,1024,1><<<dim3(64,4), dim3(256), 0, stream>>>(
        mid, w2T + (size_t)l*256*1024, b2 + l*256, x, nullptr, nullptr, nullptr);
  }
  ln_k<1><<<dim3(BSZ*TSEQ), dim3(64), 0, stream>>>(x, lnf_g, lnf_b, nullptr, (float*)d_out);
}